// Round 18
// baseline (786.782 us; speedup 1.0000x reference)
//
#include <hip/hip_runtime.h>
#include <math.h>

// Hungarian (reference-exact degenerate JV) + MSE — ZERO-LDS inner loop.
// Anchored on r17 (bit-exact, 649us). Change vs r17:
//   * hop state (u + coords of column j1's row) moves from LDS to owner-lane
//     registers, fetched via readlane(ls). SAFE under the refined rule:
//     cross-lane reads of registers are coherent iff the registers are only
//     ever written by FULL-EXEC straight-line ops (cndmask selects, pk adds)
//     — never under divergent exec. Evidence: sv (cndmask-mutated each step)
//     has fed cross-lane DPP/ballots bit-exactly since r11; readlane(bk,ls)
//     same-step temp works (r17). r2/r3/r9 failures all had divergent
//     `if(lane==..){reg=..}` writes — that class remains banned.
//   * ua[k] (u of my column's row — r12 invariant) needs no LDS flush;
//     cx/cy[k] coords set at augment from wave-uniform rix/riy via cndmask.
//   * LDS deleted entirely (MSE gather is register-local too); no barriers.
//   * fail-fast guard kept: theory-wrong => wrong answer, never a hang.
// Everything else: r17 structure (lane-major columns, one-ballot argmin,
// DPP value-min + permlane-swap tail, delta==gmin, sv==-inf predicate,
// pk f64 updates, am SGPR masks, raw v_sqrt_f32).

#define N 256

typedef double dbl2 __attribute__((ext_vector_type(2)));

static __device__ __forceinline__ int f2i(float x) { union { float f; int i; } u; u.f = x; return u.i; }
static __device__ __forceinline__ float i2f(int x) { union { float f; int i; } u; u.i = x; return u.f; }
static __device__ __forceinline__ double mkd(int lo, int hi) {
  union { unsigned long long u; double d; } w;
  w.u = (((unsigned long long)(unsigned)hi) << 32) | (unsigned)lo;
  return w.d;
}
static __device__ __forceinline__ int dlo(double d) { union { double d; unsigned long long u; } w; w.d = d; return (int)(unsigned)w.u; }
static __device__ __forceinline__ int dhi(double d) { union { double d; unsigned long long u; } w; w.d = d; return (int)(unsigned)(w.u >> 32); }

#if __has_builtin(__builtin_amdgcn_sqrtf)
#define FAST_SQRT(x) __builtin_amdgcn_sqrtf(x)
#else
#define FAST_SQRT(x) sqrtf(x)
#endif

#if __has_builtin(__builtin_amdgcn_permlane16_swap) && __has_builtin(__builtin_amdgcn_permlane32_swap)
#define HAVE_PL_SWAP 1
#else
#define HAVE_PL_SWAP 0
#endif

#define DPP_MIN_STAGE(CTRL, RMASK)                                              \
  {                                                                             \
    int mlo = dlo(bm), mhi = dhi(bm);                                           \
    int slo = __builtin_amdgcn_update_dpp(mlo, mlo, CTRL, RMASK, 0xF, false);   \
    int shi = __builtin_amdgcn_update_dpp(mhi, mhi, CTRL, RMASK, 0xF, false);   \
    bm = fmin(bm, mkd(slo, shi));                                               \
  }

__global__ __launch_bounds__(64) void hung_kernel(const float* __restrict__ pred,
                                                  const float* __restrict__ target,
                                                  double* __restrict__ partial) {
  const int b = blockIdx.x;
  const int lane = threadIdx.x;  // single wave per block

  // Column data LANE-MAJOR: lane owns cols 4*lane+k (0-based), k=0..3.
  // Row data k-major: row r-1 = lane + 64k (read-only, readlane).
  float tx[4], ty[4], rpx[4], rpy[4];
  dbl2 v01 = {0.0, 0.0}, v23 = {0.0, 0.0};    // true column duals
  dbl2 sv01 = {0.0, 0.0}, sv23 = {0.0, 0.0};  // scan duals (-inf = marked)
  dbl2 ua01 = {0.0, 0.0}, ua23 = {0.0, 0.0};  // u of my column's row (invariant)
  float cx[4] = {0.f, 0.f, 0.f, 0.f};         // coords of my column's row
  float cy[4] = {0.f, 0.f, 0.f, 0.f};         // (set at augment, full-exec)

  const float2* pv = (const float2*)pred + (size_t)b * N;
  const float2* tv = (const float2*)target + (size_t)b * N;
  {  // target coords: two float4 loads (4 consecutive float2s per lane)
    float4 t01 = ((const float4*)tv)[2 * lane];
    float4 t23 = ((const float4*)tv)[2 * lane + 1];
    tx[0] = t01.x; ty[0] = t01.y; tx[1] = t01.z; ty[1] = t01.w;
    tx[2] = t23.x; ty[2] = t23.y; tx[3] = t23.z; ty[3] = t23.w;
  }
#pragma unroll
  for (int k = 0; k < 4; ++k) {  // pred rows, k-major (coalesced float2)
    float2 pp = pv[lane + 64 * k];
    rpx[k] = pp.x; rpy[k] = pp.y;
  }

  // wave-uniform assigned masks: bit 'fl' of am_k <=> col 4*fl+k assigned
  unsigned long long am0 = 0, am1 = 0, am2 = 0, am3 = 0;
  const double NINF = -__builtin_huge_val();

  for (int i = 1; i <= N; ++i) {
    double uv0 = 0.0;  // live u[i] (virtual column 0), wave-uniform
    double ui0 = 0.0;  // row-start u of current i0; row i itself starts at 0
    float pxi, pyi, rix, riy;
    {
      const int rl = (i - 1) & 63, rs = (i - 1) >> 6;
      pxi = i2f(__builtin_amdgcn_readlane(
          rs == 0 ? f2i(rpx[0]) : rs == 1 ? f2i(rpx[1]) : rs == 2 ? f2i(rpx[2]) : f2i(rpx[3]), rl));
      pyi = i2f(__builtin_amdgcn_readlane(
          rs == 0 ? f2i(rpy[0]) : rs == 1 ? f2i(rpy[1]) : rs == 2 ? f2i(rpy[2]) : f2i(rpy[3]), rl));
      rix = pxi; riy = pyi;  // saved for the augment
    }

    int jfl, jfs;        // final column: lane / slot
    int guard = N + 2;   // fail-fast bound; off-chain scalar
    while (true) {
      // ---- scan my 4 columns, maskless: marked have sv=-inf -> m=+inf
      float dx0 = pxi - tx[0], dy0 = pyi - ty[0];
      float dx1 = pxi - tx[1], dy1 = pyi - ty[1];
      float dx2 = pxi - tx[2], dy2 = pyi - ty[2];
      float dx3 = pxi - tx[3], dy3 = pyi - ty[3];
      float c0 = FAST_SQRT(dx0 * dx0 + dy0 * dy0);
      float c1 = FAST_SQRT(dx1 * dx1 + dy1 * dy1);
      float c2 = FAST_SQRT(dx2 * dx2 + dy2 * dy2);
      float c3 = FAST_SQRT(dx3 * dx3 + dy3 * dy3);
      const dbl2 ui2 = {ui0, ui0};
      dbl2 c01 = {(double)c0, (double)c1};
      dbl2 c23 = {(double)c2, (double)c3};
      const dbl2 m01 = (c01 - ui2) - sv01;  // reference rounding order
      const dbl2 m23 = (c23 - ui2) - sv23;
      const double bml = fmin(fmin(m01.x, m01.y), fmin(m23.x, m23.y));

      // bk = first k with m[k]==bml (off-chain; overlaps the DPP stages)
      const int bk = (m01.x == bml) ? 0 : (m01.y == bml) ? 1 : (m23.x == bml) ? 2 : 3;

      // ---- wave value-min: 4 DPP butterfly stages + 2 all-lane swap stages
      double bm = bml;
      DPP_MIN_STAGE(0xB1, 0xF);   // quad_perm [1,0,3,2]  (xor 1)
      DPP_MIN_STAGE(0x4E, 0xF);   // quad_perm [2,3,0,1]  (xor 2)
      DPP_MIN_STAGE(0x141, 0xF);  // row_half_mirror      (xor 4)
      DPP_MIN_STAGE(0x140, 0xF);  // row_mirror           (xor 8)
#if HAVE_PL_SWAP
      {
        int mlo = dlo(bm), mhi = dhi(bm);
        auto rlo = __builtin_amdgcn_permlane16_swap(mlo, mlo, false, false);
        auto rhi = __builtin_amdgcn_permlane16_swap(mhi, mhi, false, false);
        bm = fmin(mkd(rlo[0], rhi[0]), mkd(rlo[1], rhi[1]));
      }
      {
        int mlo = dlo(bm), mhi = dhi(bm);
        auto rlo = __builtin_amdgcn_permlane32_swap(mlo, mlo, false, false);
        auto rhi = __builtin_amdgcn_permlane32_swap(mhi, mhi, false, false);
        bm = fmin(mkd(rlo[0], rhi[0]), mkd(rlo[1], rhi[1]));
      }
      const double delta = bm;  // global min in EVERY lane
#else
      DPP_MIN_STAGE(0x142, 0xA);
      DPP_MIN_STAGE(0x143, 0xC);
      const double delta = mkd(__builtin_amdgcn_readlane(dlo(bm), 63),
                               __builtin_amdgcn_readlane(dhi(bm), 63));
#endif

      // ---- first-index argmin, lane-major: ONE ballot + ffs + readlane(bk)
      const unsigned long long L = __ballot(bml == delta);
      const int ls = (__ffsll(L) - 1) & 63;
      const int bks = __builtin_amdgcn_readlane(bk, ls) & 3;  // same-step temp

      // ---- hop state via register readlane (owner-lane, full-exec-written)
      const double usel = bks == 0 ? ua01.x : bks == 1 ? ua01.y : bks == 2 ? ua23.x : ua23.y;
      const float cxs = bks == 0 ? cx[0] : bks == 1 ? cx[1] : bks == 2 ? cx[2] : cx[3];
      const float cys = bks == 0 ? cy[0] : bks == 1 ? cy[1] : bks == 2 ? cy[2] : cy[3];
      const double uj = mkd(__builtin_amdgcn_readlane(dlo(usel), ls),
                            __builtin_amdgcn_readlane(dhi(usel), ls));
      const float cjx = i2f(__builtin_amdgcn_readlane(f2i(cxs), ls));
      const float cjy = i2f(__builtin_amdgcn_readlane(f2i(cys), ls));

      // ---- dual update (exact sequential rounding; marked <=> sv == -inf)
      uv0 += delta;
      {
        const dbl2 a01 = {sv01.x == NINF ? delta : 0.0, sv01.y == NINF ? delta : 0.0};
        const dbl2 a23 = {sv23.x == NINF ? delta : 0.0, sv23.y == NINF ? delta : 0.0};
        v01 -= a01; ua01 += a01;
        v23 -= a23; ua23 += a23;
      }

      // ---- loop exit: scalar bit test on assigned-masks (+ guard)
      const unsigned long long am = bks == 0 ? am0 : bks == 1 ? am1 : bks == 2 ? am2 : am3;
      if (!((am >> ls) & 1) || --guard == 0) { jfl = ls; jfs = bks; break; }

      // ---- mark j1: branchless (full-exec cndmask) owner-lane sv = -inf
      const bool hit = (lane == ls);
      sv01.x = (hit && bks == 0) ? NINF : sv01.x;
      sv01.y = (hit && bks == 1) ? NINF : sv01.y;
      sv23.x = (hit && bks == 2) ? NINF : sv23.x;
      sv23.y = (hit && bks == 3) ? NINF : sv23.y;
      // ---- hop to j1's row
      ui0 = uj;
      pxi = cjx; pyi = cjy;
    }

    // ---- augment: masks + owner-lane {u, coords} via full-exec cndmask
    {
      const unsigned long long bit = 1ull << jfl;
      if (jfs == 0) am0 |= bit; else if (jfs == 1) am1 |= bit;
      else if (jfs == 2) am2 |= bit; else am3 |= bit;
      const bool ahit = (lane == jfl);
      ua01.x = (ahit && jfs == 0) ? uv0 : ua01.x;
      ua01.y = (ahit && jfs == 1) ? uv0 : ua01.y;
      ua23.x = (ahit && jfs == 2) ? uv0 : ua23.x;
      ua23.y = (ahit && jfs == 3) ? uv0 : ua23.y;
#pragma unroll
      for (int k = 0; k < 4; ++k) {
        const bool selk = ahit && (jfs == k);
        cx[k] = selk ? rix : cx[k];
        cy[k] = selk ? riy : cy[k];
      }
    }
    // ---- restore scan duals (all columns unmarked again)
    sv01 = v01; sv23 = v23;
  }

  // ---- partial MSE: my columns 4*lane+k; matched-row coords in cx/cy
  double s = 0.0;
#pragma unroll
  for (int k = 0; k < 4; ++k) {
    double dx = (double)cx[k] - (double)tx[k];
    double dy = (double)cy[k] - (double)ty[k];
    s += dx * dx + dy * dy;
  }
#pragma unroll
  for (int off = 1; off < 64; off <<= 1) s += __shfl_xor(s, off);
  if (lane == 0) partial[b] = s;
}

__global__ __launch_bounds__(64) void reduce_kernel(const double* __restrict__ partial,
                                                    float* __restrict__ out, int B) {
  double s = 0.0;
  for (int i = threadIdx.x; i < B; i += 64) s += partial[i];
#pragma unroll
  for (int off = 1; off < 64; off <<= 1) s += __shfl_xor(s, off);
  if (threadIdx.x == 0) out[0] = (float)(s / (double)(B * N * 2));
}

extern "C" void kernel_launch(void* const* d_in, const int* in_sizes, int n_in,
                              void* d_out, int out_size, void* d_ws, size_t ws_size,
                              hipStream_t stream) {
  const float* pred = (const float*)d_in[0];
  const float* target = (const float*)d_in[1];
  float* out = (float*)d_out;
  double* partial = (double*)d_ws;

  const int B = in_sizes[0] / (N * 2);  // 32

  hipLaunchKernelGGL(hung_kernel, dim3(B), dim3(64), 0, stream, pred, target, partial);
  hipLaunchKernelGGL(reduce_kernel, dim3(1), dim3(64), 0, stream, partial, out, B);
}

// Round 19
// 653.584 us; speedup vs baseline: 1.2038x; 1.2038x over previous
//
#include <hip/hip_runtime.h>
#include <math.h>

// Hungarian (reference-exact degenerate JV) + MSE.
// Anchored on r17 (bit-exact, 649us). r18's register-hop REGRESSED (787us:
// serial readlane chain beat by r17's early-issued, latency-hidden ds_read)
// and is reverted. ONE change vs r17:
//   * bk readlane ELIMINATED from the hop-address chain: bit-plane ballots
//     B0=ballot(bk&1), B1=ballot(bk&2) are delta-independent (issue during
//     the DPP reduction, off-chain); bks = bit-extract at lane ls via SALU.
//     Same first-index (lane,k) argmin; ds_read issues ~25cy earlier.
// Everything else byte-identical to r17 (lane-major columns, SoA LDS hop,
// DPP value-min + permlane-swap tail, delta==gmin, sv==-inf predicate,
// pk f64 updates, am SGPR masks, uacc invariant + b128 flush, fail-fast
// guard, raw v_sqrt_f32).
// HARD RULE (r2/r3/r9 + r18 perf): cross-lane mutable persistent state moves
// via LDS live reads with EARLY-ISSUED addresses; readlane only for
// read-only data or same-step temporaries, and never on the address chain.

#define N 256

typedef double dbl2 __attribute__((ext_vector_type(2)));

static __device__ __forceinline__ int f2i(float x) { union { float f; int i; } u; u.f = x; return u.i; }
static __device__ __forceinline__ float i2f(int x) { union { float f; int i; } u; u.i = x; return u.f; }
static __device__ __forceinline__ double mkd(int lo, int hi) {
  union { unsigned long long u; double d; } w;
  w.u = (((unsigned long long)(unsigned)hi) << 32) | (unsigned)lo;
  return w.d;
}
static __device__ __forceinline__ int dlo(double d) { union { double d; unsigned long long u; } w; w.d = d; return (int)(unsigned)w.u; }
static __device__ __forceinline__ int dhi(double d) { union { double d; unsigned long long u; } w; w.d = d; return (int)(unsigned)(w.u >> 32); }

#if __has_builtin(__builtin_amdgcn_sqrtf)
#define FAST_SQRT(x) __builtin_amdgcn_sqrtf(x)
#else
#define FAST_SQRT(x) sqrtf(x)
#endif

#if __has_builtin(__builtin_amdgcn_permlane16_swap) && __has_builtin(__builtin_amdgcn_permlane32_swap)
#define HAVE_PL_SWAP 1
#else
#define HAVE_PL_SWAP 0
#endif

#define DPP_MIN_STAGE(CTRL, RMASK)                                              \
  {                                                                             \
    int mlo = dlo(bm), mhi = dhi(bm);                                           \
    int slo = __builtin_amdgcn_update_dpp(mlo, mlo, CTRL, RMASK, 0xF, false);   \
    int shi = __builtin_amdgcn_update_dpp(mhi, mhi, CTRL, RMASK, 0xF, false);   \
    bm = fmin(bm, mkd(slo, shi));                                               \
  }

__global__ __launch_bounds__(64) void hung_kernel(const float* __restrict__ pred,
                                                  const float* __restrict__ target,
                                                  double* __restrict__ partial) {
  const int b = blockIdx.x;
  const int lane = threadIdx.x;  // single wave per block

  __shared__ double u_lds[N];   // u of the row assigned to column (0-based j)
  __shared__ float2 c_lds[N];   // pred coords of that row

  // Column data LANE-MAJOR: lane owns cols 4*lane+k (0-based), k=0..3.
  // Row data k-major: row r-1 = lane + 64k (read-only, readlane).
  float tx[4], ty[4], rpx[4], rpy[4];
  dbl2 v01 = {0.0, 0.0}, v23 = {0.0, 0.0};        // true column duals
  dbl2 sv01 = {0.0, 0.0}, sv23 = {0.0, 0.0};      // scan duals (-inf = marked)
  dbl2 ua01 = {0.0, 0.0}, ua23 = {0.0, 0.0};      // uacc invariant

  const float2* pv = (const float2*)pred + (size_t)b * N;
  const float2* tv = (const float2*)target + (size_t)b * N;
  {  // target coords: two float4 loads (4 consecutive float2s per lane)
    float4 t01 = ((const float4*)tv)[2 * lane];
    float4 t23 = ((const float4*)tv)[2 * lane + 1];
    tx[0] = t01.x; ty[0] = t01.y; tx[1] = t01.z; ty[1] = t01.w;
    tx[2] = t23.x; ty[2] = t23.y; tx[3] = t23.z; ty[3] = t23.w;
  }
#pragma unroll
  for (int k = 0; k < 4; ++k) {  // pred rows, k-major (coalesced float2)
    float2 pp = pv[lane + 64 * k];
    rpx[k] = pp.x; rpy[k] = pp.y;
  }
#pragma unroll
  for (int k = 0; k < 4; ++k) {
    int j = lane + 64 * k;
    u_lds[j] = 0.0; c_lds[j] = make_float2(0.f, 0.f);
  }
  __syncthreads();

  // wave-uniform assigned masks: bit 'fl' of am_k <=> col 4*fl+k assigned
  unsigned long long am0 = 0, am1 = 0, am2 = 0, am3 = 0;
  const double NINF = -__builtin_huge_val();

  for (int i = 1; i <= N; ++i) {
    double uv0 = 0.0;  // live u[i] (virtual column 0), wave-uniform
    double ui0 = 0.0;  // row-start u of current i0; row i itself starts at 0
    float pxi, pyi, rix, riy;
    {
      const int rl = (i - 1) & 63, rs = (i - 1) >> 6;
      pxi = i2f(__builtin_amdgcn_readlane(
          rs == 0 ? f2i(rpx[0]) : rs == 1 ? f2i(rpx[1]) : rs == 2 ? f2i(rpx[2]) : f2i(rpx[3]), rl));
      pyi = i2f(__builtin_amdgcn_readlane(
          rs == 0 ? f2i(rpy[0]) : rs == 1 ? f2i(rpy[1]) : rs == 2 ? f2i(rpy[2]) : f2i(rpy[3]), rl));
      rix = pxi; riy = pyi;  // saved for the augment store
    }

    int jfin0;
    int guard = N + 2;  // fail-fast bound; off-chain scalar
    while (true) {
      // ---- scan my 4 columns, maskless: marked have sv=-inf -> m=+inf
      float dx0 = pxi - tx[0], dy0 = pyi - ty[0];
      float dx1 = pxi - tx[1], dy1 = pyi - ty[1];
      float dx2 = pxi - tx[2], dy2 = pyi - ty[2];
      float dx3 = pxi - tx[3], dy3 = pyi - ty[3];
      float c0 = FAST_SQRT(dx0 * dx0 + dy0 * dy0);
      float c1 = FAST_SQRT(dx1 * dx1 + dy1 * dy1);
      float c2 = FAST_SQRT(dx2 * dx2 + dy2 * dy2);
      float c3 = FAST_SQRT(dx3 * dx3 + dy3 * dy3);
      const dbl2 ui2 = {ui0, ui0};
      dbl2 c01 = {(double)c0, (double)c1};
      dbl2 c23 = {(double)c2, (double)c3};
      const dbl2 m01 = (c01 - ui2) - sv01;  // reference rounding order
      const dbl2 m23 = (c23 - ui2) - sv23;
      const double bml = fmin(fmin(m01.x, m01.y), fmin(m23.x, m23.y));

      // bk = first k with m[k]==bml; bit-plane ballots are delta-independent
      // (issue during the DPP stages, off the critical chain)
      const int bk = (m01.x == bml) ? 0 : (m01.y == bml) ? 1 : (m23.x == bml) ? 2 : 3;
      const unsigned long long B0 = __ballot((bk & 1) != 0);
      const unsigned long long B1 = __ballot((bk & 2) != 0);

      // ---- wave value-min: 4 DPP butterfly stages + 2 all-lane swap stages
      double bm = bml;
      DPP_MIN_STAGE(0xB1, 0xF);   // quad_perm [1,0,3,2]  (xor 1)
      DPP_MIN_STAGE(0x4E, 0xF);   // quad_perm [2,3,0,1]  (xor 2)
      DPP_MIN_STAGE(0x141, 0xF);  // row_half_mirror      (xor 4)
      DPP_MIN_STAGE(0x140, 0xF);  // row_mirror           (xor 8)
#if HAVE_PL_SWAP
      {
        int mlo = dlo(bm), mhi = dhi(bm);
        auto rlo = __builtin_amdgcn_permlane16_swap(mlo, mlo, false, false);
        auto rhi = __builtin_amdgcn_permlane16_swap(mhi, mhi, false, false);
        bm = fmin(mkd(rlo[0], rhi[0]), mkd(rlo[1], rhi[1]));
      }
      {
        int mlo = dlo(bm), mhi = dhi(bm);
        auto rlo = __builtin_amdgcn_permlane32_swap(mlo, mlo, false, false);
        auto rhi = __builtin_amdgcn_permlane32_swap(mhi, mhi, false, false);
        bm = fmin(mkd(rlo[0], rhi[0]), mkd(rlo[1], rhi[1]));
      }
      const double delta = bm;  // global min in EVERY lane
#else
      DPP_MIN_STAGE(0x142, 0xA);
      DPP_MIN_STAGE(0x143, 0xC);
      const double delta = mkd(__builtin_amdgcn_readlane(dlo(bm), 63),
                               __builtin_amdgcn_readlane(dhi(bm), 63));
#endif

      // ---- first-index argmin: ONE on-chain ballot + ffs + SALU bit-extract
      const unsigned long long L = __ballot(bml == delta);
      const int ls = (__ffsll(L) - 1) & 63;
      const int bks = (int)(((B0 >> ls) & 1) | (((B1 >> ls) & 1) << 1));
      const int j1i = 4 * ls + bks;  // 0-based column

      // ---- hop reads: two PARALLEL uniform LDS loads; consumed next scan
      const double uj = u_lds[j1i];
      const float2 cj = c_lds[j1i];

      // ---- dual update (exact sequential rounding; marked <=> sv == -inf)
      uv0 += delta;
      {
        const dbl2 a01 = {sv01.x == NINF ? delta : 0.0, sv01.y == NINF ? delta : 0.0};
        const dbl2 a23 = {sv23.x == NINF ? delta : 0.0, sv23.y == NINF ? delta : 0.0};
        v01 -= a01; ua01 += a01;
        v23 -= a23; ua23 += a23;
      }

      // ---- loop exit: scalar bit test on assigned-masks (+ guard)
      const unsigned long long am = bks == 0 ? am0 : bks == 1 ? am1 : bks == 2 ? am2 : am3;
      if (!((am >> ls) & 1) || --guard == 0) { jfin0 = j1i; break; }

      // ---- mark j1: branchless owner-lane sv = -inf
      const bool hit = (lane == ls);
      sv01.x = (hit && bks == 0) ? NINF : sv01.x;
      sv01.y = (hit && bks == 1) ? NINF : sv01.y;
      sv23.x = (hit && bks == 2) ? NINF : sv23.x;
      sv23.y = (hit && bks == 3) ? NINF : sv23.y;
      // ---- hop to j1's row
      ui0 = uj;
      pxi = cj.x; pyi = cj.y;
    }

    // ---- augment: masks + uacc invariant for jfin's owner, coords store
    {
      const int fl = (jfin0 >> 2) & 63, fs = jfin0 & 3;
      const unsigned long long bit = 1ull << fl;
      if (fs == 0) am0 |= bit; else if (fs == 1) am1 |= bit;
      else if (fs == 2) am2 |= bit; else am3 |= bit;
      const bool ahit = (lane == fl);
      ua01.x = (ahit && fs == 0) ? uv0 : ua01.x;
      ua01.y = (ahit && fs == 1) ? uv0 : ua01.y;
      ua23.x = (ahit && fs == 2) ? uv0 : ua23.x;
      ua23.y = (ahit && fs == 3) ? uv0 : ua23.y;
    }
    c_lds[jfin0] = make_float2(rix, riy);  // wave-uniform store
    // ---- flush invariant: two aligned contiguous ds_write_b128 per lane
    *(dbl2*)&u_lds[4 * lane] = ua01;
    *(dbl2*)&u_lds[4 * lane + 2] = ua23;
    // ---- restore scan duals
    sv01 = v01; sv23 = v23;
    __builtin_amdgcn_wave_barrier();  // row-end ordering point (free)
  }

  __syncthreads();
  // ---- partial MSE: my columns 4*lane+k; matched-row coords in c_lds
  double s = 0.0;
  {
    float4 cc01 = *(const float4*)&c_lds[4 * lane];
    float4 cc23 = *(const float4*)&c_lds[4 * lane + 2];
    double dx, dy;
    dx = (double)cc01.x - (double)tx[0]; dy = (double)cc01.y - (double)ty[0]; s += dx * dx + dy * dy;
    dx = (double)cc01.z - (double)tx[1]; dy = (double)cc01.w - (double)ty[1]; s += dx * dx + dy * dy;
    dx = (double)cc23.x - (double)tx[2]; dy = (double)cc23.y - (double)ty[2]; s += dx * dx + dy * dy;
    dx = (double)cc23.z - (double)tx[3]; dy = (double)cc23.w - (double)ty[3]; s += dx * dx + dy * dy;
  }
#pragma unroll
  for (int off = 1; off < 64; off <<= 1) s += __shfl_xor(s, off);
  if (lane == 0) partial[b] = s;
}

__global__ __launch_bounds__(64) void reduce_kernel(const double* __restrict__ partial,
                                                    float* __restrict__ out, int B) {
  double s = 0.0;
  for (int i = threadIdx.x; i < B; i += 64) s += partial[i];
#pragma unroll
  for (int off = 1; off < 64; off <<= 1) s += __shfl_xor(s, off);
  if (threadIdx.x == 0) out[0] = (float)(s / (double)(B * N * 2));
}

extern "C" void kernel_launch(void* const* d_in, const int* in_sizes, int n_in,
                              void* d_out, int out_size, void* d_ws, size_t ws_size,
                              hipStream_t stream) {
  const float* pred = (const float*)d_in[0];
  const float* target = (const float*)d_in[1];
  float* out = (float*)d_out;
  double* partial = (double*)d_ws;

  const int B = in_sizes[0] / (N * 2);  // 32

  hipLaunchKernelGGL(hung_kernel, dim3(B), dim3(64), 0, stream, pred, target, partial);
  hipLaunchKernelGGL(reduce_kernel, dim3(1), dim3(64), 0, stream, partial, out, B);
}